// Round 14
// baseline (30.079 us; speedup 1.0000x reference)
//
#include <hip/hip_runtime.h>
#include <hip/hip_bf16.h>

// NT-Xent loss, MI355X. B=4096, D=256, N=8192, temp=0.5.
// R14 = R13 (MX-fp4, 32-row waves, 4 waves/SIMD, zero-tail 1024-block grid)
// + FULL-STEP B preload: all 8 slices (8 x ds_read_b128 = 32 VGPR) issued at
// step start into b[8], statically indexed by the unrolled jt loop. Depth-1
// (b0/b1) left each slice's ds_read->MFMA latency (~120cyc + 16-wave queue)
// partially exposed; 8 reads in flight amortize it to once per step.
// Poles/CU: MFMA 4.8us, LDS 5.1, trans 3.4, VALU ~2.5; R13 measured ~23us
// gram = above serial sum -> latency exposure was the residual target.

typedef __attribute__((ext_vector_type(4))) float f32x4;
typedef __attribute__((ext_vector_type(8))) int i32x8;

#define N_TOT 8192
#define B_HALF 4096
#define D_DIM 256
#define JSPLIT 16
#define JCOLS 512
#define NSTEP 8
#define SCL_PRE 1.6986436f             // sqrt((1/T)*log2 e) = sqrt(2.8853901)
#define RES_SCALE 0.6931471805599453f  // ln2: sim = acc * ln2 after prescale
#define S4 0x7B7B7B7B                  // E8M0 123 -> 2^-4 per operand

__device__ inline float fexp2(float x) {
#if __has_builtin(__builtin_amdgcn_exp2f)
  return __builtin_amdgcn_exp2f(x);  // raw v_exp_f32; args in [-3.2, 3.2]
#else
  return exp2f(x);
#endif
}

// e2m1 encode, RNE against grid {0,.5,1,1.5,2,3,4,6}, clamp at 6
__device__ inline unsigned enc4(float v) {
  float av = fabsf(v);
  unsigned c = (av >= 0.25f) + (av >= 0.75f) + (av >= 1.25f) + (av >= 1.75f) +
               (av >= 2.5f) + (av >= 3.5f) + (av >= 5.0f);
  return c | ((v < 0.f) ? 8u : 0u);
}

__device__ inline i32x8 ld16z(const char* p) {
  int4 lo = *reinterpret_cast<const int4*>(p);
  i32x8 r = {lo.x, lo.y, lo.z, lo.w, 0, 0, 0, 0};  // fp4 uses low 4 regs
  return r;
}

__global__ __launch_bounds__(256) void nrm_kernel(const float* __restrict__ z1,
                                                  const float* __restrict__ z2,
                                                  unsigned short* __restrict__ zn4) {
  int row = blockIdx.x * 4 + (threadIdx.x >> 6);
  int lane = threadIdx.x & 63;
  const float* src = (row < B_HALF) ? (z1 + (size_t)row * D_DIM)
                                    : (z2 + (size_t)(row - B_HALF) * D_DIM);
  f32x4 v = *reinterpret_cast<const f32x4*>(src + lane * 4);
  float ss = v.x * v.x + v.y * v.y + v.z * v.z + v.w * v.w;
#pragma unroll
  for (int m = 32; m >= 1; m >>= 1) ss += __shfl_xor(ss, m);
  // normalize + exp2 prescale + fp4 grid fill (x16, compensated by S4 scales)
  float inv = (SCL_PRE * 16.0f) / fmaxf(sqrtf(ss), 1e-8f);
  unsigned n0 = enc4(v.x * inv), n1 = enc4(v.y * inv);
  unsigned n2 = enc4(v.z * inv), n3 = enc4(v.w * inv);
  zn4[(size_t)row * 64 + lane] =
      (unsigned short)(n0 | (n1 << 4) | (n2 << 8) | (n3 << 12));
}

__global__ __launch_bounds__(256, 4) void gram_kernel(const unsigned short* __restrict__ zn4,
                                                      float* __restrict__ psum,
                                                      float* __restrict__ ppos) {
  __shared__ __align__(16) char bt[2 * 64 * 128];  // double-buffered fp4 B panels
  const int tid = threadIdx.x;
  const int w = tid >> 6, l = tid & 63;
  const int lm = l & 15, hh = l >> 4;
  const int r0w = blockIdx.x * 128 + w * 32;  // this wave's 32 i-rows
  const int jbase = blockIdx.y * JCOLS;
  const char* znb = reinterpret_cast<const char*>(zn4);

  // stage step s (64 B-rows x 128B fp4) into buffer bi. LDS dest linear
  // (uniform base + lane*16); swizzle via XOR on the global source unit.
  auto stage = [&](int s, int bi) {
    const char* gs = znb + (size_t)(jbase + s * 64) * 128;
    char* base = bt + bi * 8192 + w * 1024;
#pragma unroll
    for (int q = 0; q < 2; ++q) {
      int rloc = q * 32 + w * 8 + (l >> 3);
      int d = l & 7;  // dest 16B unit within the row
      const char* g = gs + (size_t)rloc * 128 + ((d ^ (rloc & 7)) << 4);
      __builtin_amdgcn_global_load_lds(
          (const __attribute__((address_space(1))) void*)g,
          (__attribute__((address_space(3))) void*)(base + q * 4096), 16, 0, 0);
    }
  };

  stage(0, 0);  // prefetch first panel; overlaps the A-fragment loads below

  // A fragments: 32 rows x K=256 fp4 in registers. lane: row lm (+rf*16),
  // k-bytes sl*64 + hh*16 .. +15. B mirrors this (Gram symmetry).
  i32x8 a[2][2];
#pragma unroll
  for (int rf = 0; rf < 2; ++rf)
#pragma unroll
    for (int sl = 0; sl < 2; ++sl)
      a[rf][sl] = ld16z(znb + (size_t)(r0w + rf * 16 + lm) * 128 + sl * 64 + hh * 16);

  float sume[2][4];
#pragma unroll
  for (int rf = 0; rf < 2; ++rf)
#pragma unroll
    for (int t = 0; t < 4; ++t) sume[rf][t] = 0.f;

  const int swz = (lm & 7) << 4;  // row = jt*16+lm -> row&7 == lm&7

  f32x4 acA[2], acB[2];  // ping-pong accumulators (static indexing)
  int pjtb = -1;

  // read one B slice: 16 cols x K=128 = 16B/lane, one swizzled ds_read_b128
  auto readS = [&](const char* bp, int jt, int sl, i32x8& b) {
    const char* row = bp + (jt * 16 + lm) * 128;
    int cs = (sl * 64 + hh * 16) ^ swz;
    b = ld16z(row + cs);
  };

  // epilogue of a finished tile: exp + LSE partial + diag mask + positive
  auto epilogue = [&](const f32x4 (&pa)[2], int jtb) {
#pragma unroll
    for (int rf = 0; rf < 2; ++rf) {
      const int itb = r0w + rf * 16;
      const bool dg = (itb == jtb);
      const bool ps = ((itb ^ B_HALF) == jtb);
      if (dg | ps) {  // wave-uniform; rare special tiles
#pragma unroll
        for (int t = 0; t < 4; ++t) {
          float sv = pa[rf][t];
          float e = fexp2(sv);
          bool self = (lm == hh * 4 + t);  // C/D map: row=hh*4+t, col=lm
          if (dg && self) e = 0.f;         // mask diagonal
          sume[rf][t] += e;
          if (ps && self) ppos[itb + hh * 4 + t] = sv * RES_SCALE;
        }
      } else {
#pragma unroll
        for (int t = 0; t < 4; ++t) sume[rf][t] += fexp2(pa[rf][t]);
      }
    }
  };

  auto mfma2 = [&](f32x4 (&acc)[2], const i32x8& b, int sl) {
    __builtin_amdgcn_s_setprio(1);
#pragma unroll
    for (int rf = 0; rf < 2; ++rf)
      acc[rf] = __builtin_amdgcn_mfma_scale_f32_16x16x128_f8f6f4(
          a[rf][sl], b, acc[rf], 4, 4, 0, S4, 0, S4);  // fmt 4 = FP4
    __builtin_amdgcn_s_setprio(0);
  };

  for (int s = 0; s < NSTEP; ++s) {
    __syncthreads();  // drains my stage loads + all waves done w/ prev buf
    if (s + 1 < NSTEP) stage(s + 1, (s + 1) & 1);  // async prefetch under compute
    const char* bp = bt + (s & 1) * 8192;

    // FULL-STEP preload: all 8 B slices in flight at once (32 VGPR);
    // lgkmcnt waits then count down 7..0 across the jt loop - no per-slice
    // latency on the critical path.
    i32x8 b[8];
#pragma unroll
    for (int u = 0; u < 8; ++u) readS(bp, u >> 1, u & 1, b[u]);

#pragma unroll
    for (int jt = 0; jt < 4; ++jt) {
      f32x4(&acc)[2] = (jt & 1) ? acB : acA;
      f32x4(&prev)[2] = (jt & 1) ? acA : acB;

      if (pjtb >= 0) epilogue(prev, pjtb);  // VALU/trans under read latency
#pragma unroll
      for (int rf = 0; rf < 2; ++rf) acc[rf] = (f32x4){0.f, 0.f, 0.f, 0.f};
      mfma2(acc, b[jt * 2], 0);
      mfma2(acc, b[jt * 2 + 1], 1);
      pjtb = jbase + s * 64 + jt * 16;
    }
  }
  epilogue(acB, pjtb);  // last tile was jt=3 -> acB

  // reduce partial sums across the 16 lanes (lm) sharing each row
#pragma unroll
  for (int rf = 0; rf < 2; ++rf)
#pragma unroll
    for (int t = 0; t < 4; ++t) {
      float v = sume[rf][t];
#pragma unroll
      for (int m = 1; m < 16; m <<= 1) v += __shfl_xor(v, m);
      if (lm == 0) psum[(size_t)blockIdx.y * N_TOT + r0w + rf * 16 + hh * 4 + t] = v;
    }
}

__global__ __launch_bounds__(256) void fin1_kernel(const float* __restrict__ psum,
                                                   const float* __restrict__ ppos,
                                                   float* __restrict__ partial) {
  int i = blockIdx.x * 256 + threadIdx.x;
  float se = 0.f;
#pragma unroll
  for (int s = 0; s < JSPLIT; ++s) se += psum[(size_t)s * N_TOT + i];
  float acc = logf(se) - ppos[i];
#pragma unroll
  for (int m = 32; m >= 1; m >>= 1) acc += __shfl_xor(acc, m);
  __shared__ float red[4];
  if ((threadIdx.x & 63) == 0) red[threadIdx.x >> 6] = acc;
  __syncthreads();
  if (threadIdx.x == 0) partial[blockIdx.x] = red[0] + red[1] + red[2] + red[3];
}

__global__ void fin2_kernel(const float* __restrict__ partial, float* __restrict__ out) {
  float v = (threadIdx.x < 32) ? partial[threadIdx.x] : 0.f;
#pragma unroll
  for (int m = 32; m >= 1; m >>= 1) v += __shfl_xor(v, m);
  if (threadIdx.x == 0) out[0] = v / (float)N_TOT;
}

extern "C" void kernel_launch(void* const* d_in, const int* in_sizes, int n_in,
                              void* d_out, int out_size, void* d_ws, size_t ws_size,
                              hipStream_t stream) {
  const float* z1 = (const float*)d_in[0];
  const float* z2 = (const float*)d_in[1];
  float* out = (float*)d_out;
  char* ws = (char*)d_ws;

  unsigned short* zn4 = (unsigned short*)ws;            // 8192*128B = 1 MiB fp4
  float* psum = (float*)(ws + (size_t)N_TOT * 128);     // 16*8192 f32
  float* ppos = psum + (size_t)JSPLIT * N_TOT;          // 8192 f32
  float* partial = ppos + N_TOT;                        // 32 f32

  nrm_kernel<<<N_TOT / 4, 256, 0, stream>>>(z1, z2, zn4);
  gram_kernel<<<dim3(N_TOT / 128, JSPLIT), 256, 0, stream>>>(zn4, psum, ppos);
  fin1_kernel<<<N_TOT / 256, 256, 0, stream>>>(psum, ppos, partial);
  fin2_kernel<<<1, 64, 0, stream>>>(partial, out);
}